// Round 2
// baseline (288.013 us; speedup 1.0000x reference)
//
#include <hip/hip_runtime.h>

#define B_ 32
#define T_ 2048
#define D_ 512

// ---------------- K1: energy[b,t] = dot(key[b,t,:], q[b,:]) ----------------
// 2048 blocks (8/CU resident), 256 threads = 4 waves, 32 rows per block
// (8 rows per wave). q[b] held in registers (L1/L2-cached), no LDS/barrier.
__global__ __launch_bounds__(256) void energy_kernel(
    const float* __restrict__ q,
    const float* __restrict__ key,
    float* __restrict__ energy)
{
    const int b    = blockIdx.x >> 6;            // 64 blocks per batch
    const int t0   = (blockIdx.x & 63) * 32;     // 32 rows per block
    const int wave = threadIdx.x >> 6;
    const int lane = threadIdx.x & 63;

    const float4 qv0 = ((const float4*)q)[b * 128 + lane];
    const float4 qv1 = ((const float4*)q)[b * 128 + 64 + lane];

    const int trow = t0 + wave * 8;              // this wave's first row
    const float4* kbase = (const float4*)key + ((size_t)b * T_ + trow) * 128;

#pragma unroll 4
    for (int r = 0; r < 8; ++r) {
        const float4 k0 = kbase[r * 128 + lane];
        const float4 k1 = kbase[r * 128 + 64 + lane];
        float acc = k0.x * qv0.x + k0.y * qv0.y + k0.z * qv0.z + k0.w * qv0.w
                  + k1.x * qv1.x + k1.y * qv1.y + k1.z * qv1.z + k1.w * qv1.w;
#pragma unroll
        for (int off = 32; off >= 1; off >>= 1)
            acc += __shfl_down(acc, off);
        if (lane == 0)
            energy[b * T_ + trow + r] = acc;
    }
}

// ---------------- K2: softmax over T per batch, write attention ----------------
__global__ __launch_bounds__(256) void softmax_kernel(
    const float* __restrict__ energy,
    float* __restrict__ attn)                    // [B, T] region of d_out
{
    const int b = blockIdx.x;
    const int wave = threadIdx.x >> 6;
    const int lane = threadIdx.x & 63;

    const float4* e4 = (const float4*)(energy + b * T_);
    float4 v0 = e4[threadIdx.x * 2 + 0];
    float4 v1 = e4[threadIdx.x * 2 + 1];

    // ---- block max ----
    float m = fmaxf(fmaxf(fmaxf(v0.x, v0.y), fmaxf(v0.z, v0.w)),
                    fmaxf(fmaxf(v1.x, v1.y), fmaxf(v1.z, v1.w)));
#pragma unroll
    for (int off = 32; off >= 1; off >>= 1)
        m = fmaxf(m, __shfl_xor(m, off));
    __shared__ float redm[4];
    if (lane == 0) redm[wave] = m;
    __syncthreads();
    m = fmaxf(fmaxf(redm[0], redm[1]), fmaxf(redm[2], redm[3]));

    // ---- exp + block sum ----
    float4 x0, x1;
    x0.x = __expf(v0.x - m); x0.y = __expf(v0.y - m);
    x0.z = __expf(v0.z - m); x0.w = __expf(v0.w - m);
    x1.x = __expf(v1.x - m); x1.y = __expf(v1.y - m);
    x1.z = __expf(v1.z - m); x1.w = __expf(v1.w - m);
    float s = x0.x + x0.y + x0.z + x0.w + x1.x + x1.y + x1.z + x1.w;
#pragma unroll
    for (int off = 32; off >= 1; off >>= 1)
        s += __shfl_xor(s, off);
    __shared__ float reds[4];
    if (lane == 0) reds[wave] = s;
    __syncthreads();
    s = reds[0] + reds[1] + reds[2] + reds[3];

    const float inv = 1.f / s;
    x0.x *= inv; x0.y *= inv; x0.z *= inv; x0.w *= inv;
    x1.x *= inv; x1.y *= inv; x1.z *= inv; x1.w *= inv;

    float4* a4 = (float4*)(attn + b * T_);
    a4[threadIdx.x * 2 + 0] = x0;
    a4[threadIdx.x * 2 + 1] = x1;
}

// ---------------- K3: partial[b,chunk,:] = sum_{t in chunk} attn[b,t]*value[b,t,:] ----
// 1024 blocks (4/CU) = 32 b x 32 chunks (64 t each). 256 threads:
// 2 row-groups x 128 float4 d-slices. Wave reads 1 KiB contiguous per instr.
__global__ __launch_bounds__(256) void context_partial_kernel(
    const float* __restrict__ attn,
    const float* __restrict__ value,
    float* __restrict__ partial)                 // [B, 32, D]
{
    __shared__ float  attn_s[64];
    __shared__ float4 red4[128];

    const int b     = blockIdx.x >> 5;
    const int chunk = blockIdx.x & 31;
    const int t0    = chunk * 64;

    if (threadIdx.x < 64)
        attn_s[threadIdx.x] = attn[b * T_ + t0 + threadIdx.x];
    __syncthreads();

    const int tg = threadIdx.x >> 7;             // row group 0..1
    const int d4 = threadIdx.x & 127;            // float4 index in D

    const float4* v4 = (const float4*)value + ((size_t)b * T_ + t0 + tg) * 128 + d4;
    float4 acc = {0.f, 0.f, 0.f, 0.f};
#pragma unroll 8
    for (int i = 0; i < 32; ++i) {               // t = t0 + 2*i + tg
        const float a = attn_s[2 * i + tg];
        const float4 vv = v4[i * 256];           // stride 2 rows
        acc.x += a * vv.x; acc.y += a * vv.y;
        acc.z += a * vv.z; acc.w += a * vv.w;
    }

    if (tg == 1) red4[d4] = acc;
    __syncthreads();
    if (tg == 0) {
        const float4 o = red4[d4];
        acc.x += o.x; acc.y += o.y; acc.z += o.z; acc.w += o.w;
        ((float4*)partial)[((size_t)b * 32 + chunk) * 128 + d4] = acc;
    }
}

// ---------------- K4: out[b,:] = sum over 32 chunk partials ----------------
__global__ __launch_bounds__(128) void reduce_kernel(
    const float* __restrict__ partial,
    float* __restrict__ out)
{
    const int b  = blockIdx.x;
    const int d4 = threadIdx.x;
    float4 s = {0.f, 0.f, 0.f, 0.f};
#pragma unroll
    for (int c = 0; c < 32; ++c) {
        const float4 p = ((const float4*)partial)[((size_t)b * 32 + c) * 128 + d4];
        s.x += p.x; s.y += p.y; s.z += p.z; s.w += p.w;
    }
    ((float4*)out)[b * 128 + d4] = s;
}

extern "C" void kernel_launch(void* const* d_in, const int* in_sizes, int n_in,
                              void* d_out, int out_size, void* d_ws, size_t ws_size,
                              hipStream_t stream)
{
    const float* q     = (const float*)d_in[0];   // [B, D]
    const float* key   = (const float*)d_in[1];   // [B, T, D]
    const float* value = (const float*)d_in[2];   // [B, T, D]

    float* out  = (float*)d_out;                  // [B, D] first
    float* attn = out + B_ * D_;                  // [B, T] second

    float* energy  = (float*)d_ws;                // B*T floats     (256 KiB)
    float* partial = energy + B_ * T_;            // B*32*D floats  (2 MiB)

    energy_kernel<<<B_ * 64, 256, 0, stream>>>(q, key, energy);
    softmax_kernel<<<B_, 256, 0, stream>>>(energy, attn);
    context_partial_kernel<<<B_ * 32, 256, 0, stream>>>(attn, value, partial);
    reduce_kernel<<<B_, 128, 0, stream>>>(partial, out);
}